// Round 1
// baseline (855.767 us; speedup 1.0000x reference)
//
#include <hip/hip_runtime.h>
#include <stdint.h>

typedef short    v8s  __attribute__((ext_vector_type(8)));
typedef float    v4f  __attribute__((ext_vector_type(4)));
typedef unsigned short u16x8 __attribute__((ext_vector_type(8)));
typedef unsigned short ushort_t;

#define NB   32
#define NN   1024
#define CD   896
#define GD   384
#define HD   256
#define OD   1280

static __device__ __forceinline__ unsigned short f2bf(float f) {
    union { float f; unsigned u; } v; v.f = f;
    unsigned r = v.u + 0x7fffu + ((v.u >> 16) & 1u);
    return (unsigned short)(r >> 16);
}

// stage 16 fp32 -> 16 bf16 into LDS (two 16B stores)
static __device__ __forceinline__ void stage_cvt16(const float* __restrict__ src, ushort_t* dst) {
    const float4* s4 = (const float4*)src;
    float4 f0 = s4[0], f1 = s4[1], f2 = s4[2], f3 = s4[3];
    u16x8 p0, p1;
    p0[0]=f2bf(f0.x); p0[1]=f2bf(f0.y); p0[2]=f2bf(f0.z); p0[3]=f2bf(f0.w);
    p0[4]=f2bf(f1.x); p0[5]=f2bf(f1.y); p0[6]=f2bf(f1.z); p0[7]=f2bf(f1.w);
    p1[0]=f2bf(f2.x); p1[1]=f2bf(f2.y); p1[2]=f2bf(f2.z); p1[3]=f2bf(f2.w);
    p1[4]=f2bf(f3.x); p1[5]=f2bf(f3.y); p1[6]=f2bf(f3.z); p1[7]=f2bf(f3.w);
    *(u16x8*)dst = p0;
    *(u16x8*)(dst + 8) = p1;
}

// stage 16 bf16 -> LDS
static __device__ __forceinline__ void stage_copy16(const ushort_t* __restrict__ src, ushort_t* dst) {
    const u16x8* s = (const u16x8*)src;
    u16x8 a = s[0], b = s[1];
    *(u16x8*)dst = a;
    *(u16x8*)(dst + 8) = b;
}

// ---------------- weight transpose+convert: W[k][n] f32 -> Wt[n][k] bf16 ----
__global__ void convw_kernel(const float* __restrict__ W, ushort_t* __restrict__ Wt, int Kd) {
    int idx = blockIdx.x * 256 + threadIdx.x;      // total = Kd*256
    int k = idx >> 8, n = idx & 255;
    Wt[(size_t)n * Kd + k] = f2bf(W[idx]);
}

// ---------------- cluster pooled mean ----------------
__global__ void pool_kernel(const float* __restrict__ cf, float* __restrict__ pooled) {
    int b = blockIdx.y;
    int c = blockIdx.x * 128 + threadIdx.x;        // 0..895
    float s = 0.f;
    const float* p = cf + (size_t)b * NN * CD + c;
    for (int n = 0; n < NN; ++n) s += p[(size_t)n * CD];
    pooled[b * CD + c] = s * (1.f / 1024.f);
}

__global__ void zero_kernel(float* __restrict__ p, int n) {
    int i = blockIdx.x * 256 + threadIdx.x;
    if (i < n) p[i] = 0.f;
}

// ---------------- projection GEMM: C_bf16[M,256] = A_f32[M,KD] @ Wt^T + bias -
template<int KD>
__global__ __launch_bounds__(256) void proj_kernel(
    const float* __restrict__ A, const ushort_t* __restrict__ Wt,
    const float* __restrict__ bias, ushort_t* __restrict__ C)
{
    __shared__ ushort_t lA[128 * 40];
    __shared__ ushort_t lB[128 * 40];
    const int tid  = threadIdx.x;
    const int m0   = blockIdx.x * 128;
    const int n0   = blockIdx.y * 128;
    const int lane = tid & 63, wave = tid >> 6;
    const int l15  = lane & 15, quad = lane >> 4;
    const int wrow = (wave >> 1) * 64, wcol = (wave & 1) * 64;
    const int srow = tid >> 1, shalf = tid & 1;

    v4f acc[4][4];
    #pragma unroll
    for (int i = 0; i < 4; ++i)
        #pragma unroll
        for (int j = 0; j < 4; ++j) acc[i][j] = v4f{0.f, 0.f, 0.f, 0.f};

    for (int kt = 0; kt < KD / 32; ++kt) {
        stage_cvt16(A + (size_t)(m0 + srow) * KD + kt * 32 + shalf * 16,
                    &lA[srow * 40 + shalf * 16]);
        stage_copy16(Wt + (size_t)(n0 + srow) * KD + kt * 32 + shalf * 16,
                     &lB[srow * 40 + shalf * 16]);
        __syncthreads();
        v8s af[4], bfr[4];
        #pragma unroll
        for (int rt = 0; rt < 4; ++rt) af[rt]  = *(const v8s*)&lA[(wrow + rt * 16 + l15) * 40 + quad * 8];
        #pragma unroll
        for (int ct = 0; ct < 4; ++ct) bfr[ct] = *(const v8s*)&lB[(wcol + ct * 16 + l15) * 40 + quad * 8];
        #pragma unroll
        for (int rt = 0; rt < 4; ++rt)
            #pragma unroll
            for (int ct = 0; ct < 4; ++ct)
                acc[rt][ct] = __builtin_amdgcn_mfma_f32_16x16x32_bf16(af[rt], bfr[ct], acc[rt][ct], 0, 0, 0);
        __syncthreads();
    }

    #pragma unroll
    for (int ct = 0; ct < 4; ++ct) {
        int col = n0 + wcol + ct * 16 + l15;
        float bv = bias[col];
        #pragma unroll
        for (int rt = 0; rt < 4; ++rt)
            #pragma unroll
            for (int r = 0; r < 4; ++r) {
                int row = m0 + wrow + rt * 16 + quad * 4 + r;
                C[(size_t)row * 256 + col] = f2bf(acc[rt][ct][r] + bv);
            }
    }
}

// ---------------- V transpose: Vb[b][m][n] -> Vt[b][n][m] (bf16) ------------
__global__ __launch_bounds__(256) void transpose_v(const ushort_t* __restrict__ Vb, ushort_t* __restrict__ Vt) {
    __shared__ ushort_t t[64 * 72];
    int b = blockIdx.z, m0 = blockIdx.x * 64, n0 = blockIdx.y * 64;
    int tid = threadIdx.x;
    int r = tid >> 2, seg = tid & 3;
    stage_copy16(Vb + (size_t)(b * NN + m0 + r) * HD + n0 + seg * 16, &t[r * 72 + seg * 16]);
    __syncthreads();
    int n = tid >> 2;
    u16x8 p0, p1;
    #pragma unroll
    for (int i = 0; i < 8; ++i) p0[i] = t[(seg * 16 + i) * 72 + n];
    #pragma unroll
    for (int i = 0; i < 8; ++i) p1[i] = t[(seg * 16 + 8 + i) * 72 + n];
    ushort_t* dst = Vt + (size_t)(b * HD + n0 + n) * NN + m0 + seg * 16;
    *(u16x8*)dst = p0;
    *(u16x8*)(dst + 8) = p1;
}

// ---------------- scores: S = scale*Qb@Kb^T + log(w+1e-8) (fp32 into d_out) -
__global__ __launch_bounds__(256) void scores_kernel(
    const ushort_t* __restrict__ Qb, const ushort_t* __restrict__ Kb,
    const float* __restrict__ W, float* __restrict__ S)
{
    __shared__ ushort_t lA[128 * 40];
    __shared__ ushort_t lB[128 * 40];
    const int bat = blockIdx.z;
    const int m0 = blockIdx.x * 128, n0 = blockIdx.y * 128;
    const int tid = threadIdx.x;
    const int lane = tid & 63, wave = tid >> 6;
    const int l15 = lane & 15, quad = lane >> 4;
    const int wrow = (wave >> 1) * 64, wcol = (wave & 1) * 64;
    const int srow = tid >> 1, shalf = tid & 1;

    v4f acc[4][4];
    #pragma unroll
    for (int i = 0; i < 4; ++i)
        #pragma unroll
        for (int j = 0; j < 4; ++j) acc[i][j] = v4f{0.f, 0.f, 0.f, 0.f};

    for (int kt = 0; kt < 8; ++kt) {   // HD=256 -> 8 tiles of 32
        stage_copy16(Qb + (size_t)(bat * NN + m0 + srow) * HD + kt * 32 + shalf * 16,
                     &lA[srow * 40 + shalf * 16]);
        stage_copy16(Kb + (size_t)(bat * NN + n0 + srow) * HD + kt * 32 + shalf * 16,
                     &lB[srow * 40 + shalf * 16]);
        __syncthreads();
        v8s af[4], bfr[4];
        #pragma unroll
        for (int rt = 0; rt < 4; ++rt) af[rt]  = *(const v8s*)&lA[(wrow + rt * 16 + l15) * 40 + quad * 8];
        #pragma unroll
        for (int ct = 0; ct < 4; ++ct) bfr[ct] = *(const v8s*)&lB[(wcol + ct * 16 + l15) * 40 + quad * 8];
        #pragma unroll
        for (int rt = 0; rt < 4; ++rt)
            #pragma unroll
            for (int ct = 0; ct < 4; ++ct)
                acc[rt][ct] = __builtin_amdgcn_mfma_f32_16x16x32_bf16(af[rt], bfr[ct], acc[rt][ct], 0, 0, 0);
        __syncthreads();
    }

    const float scale = 0.0625f;  // 1/sqrt(256)
    #pragma unroll
    for (int ct = 0; ct < 4; ++ct) {
        int col = n0 + wcol + ct * 16 + l15;
        #pragma unroll
        for (int rt = 0; rt < 4; ++rt)
            #pragma unroll
            for (int r = 0; r < 4; ++r) {
                int row = m0 + wrow + rt * 16 + quad * 4 + r;
                size_t idx = ((size_t)bat << 20) + (size_t)row * NN + col;
                S[idx] = acc[rt][ct][r] * scale + __logf(W[idx] + 1e-8f);
            }
    }
}

// ---------------- softmax in place, one wave per row ------------------------
__global__ __launch_bounds__(256) void softmax_kernel(float* __restrict__ S) {
    int row  = blockIdx.x * 4 + (threadIdx.x >> 6);
    int lane = threadIdx.x & 63;
    float* base = S + (size_t)row * NN;
    float4 v[4];
    #pragma unroll
    for (int i = 0; i < 4; ++i) v[i] = *(float4*)(base + i * 256 + lane * 4);
    float m = -1e30f;
    #pragma unroll
    for (int i = 0; i < 4; ++i) m = fmaxf(m, fmaxf(fmaxf(v[i].x, v[i].y), fmaxf(v[i].z, v[i].w)));
    #pragma unroll
    for (int off = 32; off >= 1; off >>= 1) m = fmaxf(m, __shfl_xor(m, off));
    float s = 0.f;
    #pragma unroll
    for (int i = 0; i < 4; ++i) {
        v[i].x = __expf(v[i].x - m); v[i].y = __expf(v[i].y - m);
        v[i].z = __expf(v[i].z - m); v[i].w = __expf(v[i].w - m);
        s += v[i].x + v[i].y + v[i].z + v[i].w;
    }
    #pragma unroll
    for (int off = 32; off >= 1; off >>= 1) s += __shfl_xor(s, off);
    float inv = 1.0f / s;
    #pragma unroll
    for (int i = 0; i < 4; ++i) {
        v[i].x *= inv; v[i].y *= inv; v[i].z *= inv; v[i].w *= inv;
        *(float4*)(base + i * 256 + lane * 4) = v[i];
    }
}

// ---------------- pv: colsum over rows of (P @ V) -> gpool ------------------
__global__ __launch_bounds__(256) void pv_kernel(
    const float* __restrict__ P, const ushort_t* __restrict__ Vt,
    float* __restrict__ gpool)
{
    __shared__ ushort_t lA[128 * 40];
    __shared__ ushort_t lB[128 * 40];
    const int bat = blockIdx.z;
    const int m0 = blockIdx.x * 128, n0 = blockIdx.y * 128;
    const int tid = threadIdx.x;
    const int lane = tid & 63, wave = tid >> 6;
    const int l15 = lane & 15, quad = lane >> 4;
    const int wrow = (wave >> 1) * 64, wcol = (wave & 1) * 64;
    const int srow = tid >> 1, shalf = tid & 1;

    v4f acc[4][4];
    #pragma unroll
    for (int i = 0; i < 4; ++i)
        #pragma unroll
        for (int j = 0; j < 4; ++j) acc[i][j] = v4f{0.f, 0.f, 0.f, 0.f};

    for (int kt = 0; kt < 32; ++kt) {   // K = 1024
        stage_cvt16(P + ((size_t)bat << 20) + (size_t)(m0 + srow) * NN + kt * 32 + shalf * 16,
                    &lA[srow * 40 + shalf * 16]);
        stage_copy16(Vt + (size_t)(bat * HD + n0 + srow) * NN + kt * 32 + shalf * 16,
                     &lB[srow * 40 + shalf * 16]);
        __syncthreads();
        v8s af[4], bfr[4];
        #pragma unroll
        for (int rt = 0; rt < 4; ++rt) af[rt]  = *(const v8s*)&lA[(wrow + rt * 16 + l15) * 40 + quad * 8];
        #pragma unroll
        for (int ct = 0; ct < 4; ++ct) bfr[ct] = *(const v8s*)&lB[(wcol + ct * 16 + l15) * 40 + quad * 8];
        #pragma unroll
        for (int rt = 0; rt < 4; ++rt)
            #pragma unroll
            for (int ct = 0; ct < 4; ++ct)
                acc[rt][ct] = __builtin_amdgcn_mfma_f32_16x16x32_bf16(af[rt], bfr[ct], acc[rt][ct], 0, 0, 0);
        __syncthreads();
    }

    // column sums over this block's 128 rows; attended is only ever pooled.
    #pragma unroll
    for (int ct = 0; ct < 4; ++ct) {
        float sum = 0.f;
        #pragma unroll
        for (int rt = 0; rt < 4; ++rt)
            #pragma unroll
            for (int r = 0; r < 4; ++r) sum += acc[rt][ct][r];
        sum += __shfl_xor(sum, 16);
        sum += __shfl_xor(sum, 32);
        if (quad == 0) {
            int col = n0 + wcol + ct * 16 + l15;   // 0..255
            atomicAdd(&gpool[bat * HD + col], sum);
        }
    }
}

// ---------------- tails (fp32 vector) ---------------------------------------
__global__ void tail1_kernel(const float* __restrict__ pooled, const float* __restrict__ gpool,
                             const float* __restrict__ Wcp, const float* __restrict__ bcp,
                             const float* __restrict__ Wgp, const float* __restrict__ bgp,
                             float* __restrict__ combined)
{
    int idx = blockIdx.x * 256 + threadIdx.x;  // 32*1280
    int b = idx / OD, c = idx % OD;
    float acc;
    if (c < 640) {
        acc = bcp[c];
        const float* a = pooled + b * CD;
        for (int k = 0; k < CD; ++k) acc += a[k] * Wcp[k * 640 + c];
    } else {
        int c2 = c - 640;
        acc = bgp[c2];
        const float* g = gpool + b * HD;
        for (int k = 0; k < HD; ++k) acc += (g[k] * (1.f / 1024.f)) * Wgp[k * 640 + c2];
    }
    combined[idx] = acc;
}

__global__ void tail2_kernel(const float* __restrict__ combined, const float* __restrict__ Wf1,
                             const float* __restrict__ bf1,
                             const float* __restrict__ g, const float* __restrict__ be,
                             const float* __restrict__ mn, const float* __restrict__ vr,
                             float* __restrict__ h)
{
    int idx = blockIdx.x * 256 + threadIdx.x;
    int b = idx / OD, c = idx % OD;
    float acc = bf1[c];
    const float* a = combined + b * OD;
    for (int k = 0; k < OD; ++k) acc += a[k] * Wf1[k * OD + c];
    float x = (acc - mn[c]) * rsqrtf(vr[c] + 1e-5f) * g[c] + be[c];
    h[idx] = fmaxf(x, 0.f);
}

__global__ void tail3_kernel(const float* __restrict__ h, const float* __restrict__ Wf2,
                             const float* __restrict__ bf2, float* __restrict__ out)
{
    int idx = blockIdx.x * 256 + threadIdx.x;
    int b = idx / OD, c = idx % OD;
    float acc = bf2[c];
    const float* a = h + b * OD;
    for (int k = 0; k < OD; ++k) acc += a[k] * Wf2[k * OD + c];
    out[idx] = acc;
}

// ---------------- launch ----------------------------------------------------
extern "C" void kernel_launch(void* const* d_in, const int* in_sizes, int n_in,
                              void* d_out, int out_size, void* d_ws, size_t ws_size,
                              hipStream_t stream)
{
    const float* cf  = (const float*)d_in[0];
    const float* gf  = (const float*)d_in[1];
    const float* cw  = (const float*)d_in[2];
    const float* Wq  = (const float*)d_in[3];  const float* bq  = (const float*)d_in[4];
    const float* Wk  = (const float*)d_in[5];  const float* bk  = (const float*)d_in[6];
    const float* Wv  = (const float*)d_in[7];  const float* bv  = (const float*)d_in[8];
    const float* Wcp = (const float*)d_in[9];  const float* bcp = (const float*)d_in[10];
    const float* Wgp = (const float*)d_in[11]; const float* bgp = (const float*)d_in[12];
    const float* Wf1 = (const float*)d_in[13]; const float* bf1 = (const float*)d_in[14];
    const float* bng = (const float*)d_in[15]; const float* bnb = (const float*)d_in[16];
    const float* bnm = (const float*)d_in[17]; const float* bnv = (const float*)d_in[18];
    const float* Wf2 = (const float*)d_in[19]; const float* bf2 = (const float*)d_in[20];

    float* out  = (float*)d_out;         // [32,1280]
    float* attn = out + NB * OD;         // [32,1024,1024] fp32 (also scores scratch)

    char* w = (char*)d_ws;
    ushort_t* Qb  = (ushort_t*)w; w += (size_t)NB * NN * HD * 2;
    ushort_t* Kb  = (ushort_t*)w; w += (size_t)NB * NN * HD * 2;
    ushort_t* Vb  = (ushort_t*)w; w += (size_t)NB * NN * HD * 2;
    ushort_t* Vt  = (ushort_t*)w; w += (size_t)NB * NN * HD * 2;
    ushort_t* Wqt = (ushort_t*)w; w += (size_t)HD * CD * 2;
    ushort_t* Wkt = (ushort_t*)w; w += (size_t)HD * GD * 2;
    ushort_t* Wvt = (ushort_t*)w; w += (size_t)HD * GD * 2;
    float* pooled   = (float*)w; w += (size_t)NB * CD * 4;
    float* gpool    = (float*)w; w += (size_t)NB * HD * 4;
    float* combined = (float*)w; w += (size_t)NB * OD * 4;
    float* hbuf     = (float*)w; w += (size_t)NB * OD * 4;

    zero_kernel<<<dim3(32), dim3(256), 0, stream>>>(gpool, NB * HD);
    convw_kernel<<<dim3(CD), dim3(256), 0, stream>>>(Wq, Wqt, CD);
    convw_kernel<<<dim3(GD), dim3(256), 0, stream>>>(Wk, Wkt, GD);
    convw_kernel<<<dim3(GD), dim3(256), 0, stream>>>(Wv, Wvt, GD);
    pool_kernel<<<dim3(7, 32), dim3(128), 0, stream>>>(cf, pooled);

    proj_kernel<CD><<<dim3(256, 2), dim3(256), 0, stream>>>(cf, Wqt, bq, Qb);
    proj_kernel<GD><<<dim3(256, 2), dim3(256), 0, stream>>>(gf, Wkt, bk, Kb);
    proj_kernel<GD><<<dim3(256, 2), dim3(256), 0, stream>>>(gf, Wvt, bv, Vb);
    transpose_v<<<dim3(16, 4, 32), dim3(256), 0, stream>>>(Vb, Vt);

    scores_kernel<<<dim3(8, 8, 32), dim3(256), 0, stream>>>(Qb, Kb, cw, attn);
    softmax_kernel<<<dim3(8192), dim3(256), 0, stream>>>(attn);
    pv_kernel<<<dim3(8, 2, 32), dim3(256), 0, stream>>>(attn, Vt, gpool);

    tail1_kernel<<<dim3(160), dim3(256), 0, stream>>>(pooled, gpool, Wcp, bcp, Wgp, bgp, combined);
    tail2_kernel<<<dim3(160), dim3(256), 0, stream>>>(combined, Wf1, bf1, bng, bnb, bnm, bnv, hbuf);
    tail3_kernel<<<dim3(160), dim3(256), 0, stream>>>(hbuf, Wf2, bf2, out);
}

// Round 2
// 797.554 us; speedup vs baseline: 1.0730x; 1.0730x over previous
//
#include <hip/hip_runtime.h>
#include <stdint.h>

typedef short    v8s  __attribute__((ext_vector_type(8)));
typedef float    v4f  __attribute__((ext_vector_type(4)));
typedef unsigned short u16x8 __attribute__((ext_vector_type(8)));
typedef unsigned short ushort_t;

#define NB   32
#define NN   1024
#define CD   896
#define GD   384
#define HD   256
#define OD   1280
#define SP   1028   // LDS score pitch (floats): p/4 odd -> conflict-floor b128 reads

static __device__ __forceinline__ unsigned short f2bf(float f) {
    union { float f; unsigned u; } v; v.f = f;
    unsigned r = v.u + 0x7fffu + ((v.u >> 16) & 1u);
    return (unsigned short)(r >> 16);
}
// fast round-half-up (phase-3 P conversion; P in [0,1], half-ulp bias negligible)
static __device__ __forceinline__ unsigned short f2bf_fast(float f) {
    union { float f; unsigned u; } v; v.f = f;
    return (unsigned short)((v.u + 0x8000u) >> 16);
}

static __device__ __forceinline__ v4f mfma16(v8s a, v8s b, v4f c) {
    return __builtin_amdgcn_mfma_f32_16x16x32_bf16(a, b, c, 0, 0, 0);
}

// stage 16 fp32 -> 16 bf16 into LDS (two 16B stores)
static __device__ __forceinline__ void stage_cvt16(const float* __restrict__ src, ushort_t* dst) {
    const float4* s4 = (const float4*)src;
    float4 f0 = s4[0], f1 = s4[1], f2 = s4[2], f3 = s4[3];
    u16x8 p0, p1;
    p0[0]=f2bf(f0.x); p0[1]=f2bf(f0.y); p0[2]=f2bf(f0.z); p0[3]=f2bf(f0.w);
    p0[4]=f2bf(f1.x); p0[5]=f2bf(f1.y); p0[6]=f2bf(f1.z); p0[7]=f2bf(f1.w);
    p1[0]=f2bf(f2.x); p1[1]=f2bf(f2.y); p1[2]=f2bf(f2.z); p1[3]=f2bf(f2.w);
    p1[4]=f2bf(f3.x); p1[5]=f2bf(f3.y); p1[6]=f2bf(f3.z); p1[7]=f2bf(f3.w);
    *(u16x8*)dst = p0;
    *(u16x8*)(dst + 8) = p1;
}

static __device__ __forceinline__ void stage_copy16(const ushort_t* __restrict__ src, ushort_t* dst) {
    const u16x8* s = (const u16x8*)src;
    u16x8 a = s[0], b = s[1];
    *(u16x8*)dst = a;
    *(u16x8*)(dst + 8) = b;
}

// ---------------- weight transpose+convert: W[k][n] f32 -> Wt[n][k] bf16 ----
__global__ void convw_kernel(const float* __restrict__ W, ushort_t* __restrict__ Wt, int Kd) {
    int idx = blockIdx.x * 256 + threadIdx.x;      // total = Kd*256
    int k = idx >> 8, n = idx & 255;
    Wt[(size_t)n * Kd + k] = f2bf(W[idx]);
}

__global__ void zero_kernel(float* __restrict__ p, int n) {
    int i = blockIdx.x * 256 + threadIdx.x;
    if (i < n) p[i] = 0.f;
}

// ---------------- cluster pooled mean: 256 blocks, float4, atomic combine ---
__global__ void pool_kernel(const float* __restrict__ cf, float* __restrict__ pooled) {
    int b = blockIdx.y, chunk = blockIdx.x, t = threadIdx.x;
    if (t >= 224) return;                          // 224 float4 = 896 floats
    const float4* p = (const float4*)(cf + (size_t)(b * NN + chunk * 128) * CD) + t;
    float4 s = {0.f, 0.f, 0.f, 0.f};
    #pragma unroll 4
    for (int n = 0; n < 128; ++n) {
        float4 v = p[(size_t)n * 224];
        s.x += v.x; s.y += v.y; s.z += v.z; s.w += v.w;
    }
    const float sc = 1.f / 1024.f;
    float* dst = pooled + b * CD + t * 4;
    atomicAdd(dst + 0, s.x * sc);
    atomicAdd(dst + 1, s.y * sc);
    atomicAdd(dst + 2, s.z * sc);
    atomicAdd(dst + 3, s.w * sc);
}

// ---------------- projection GEMM: C_bf16[M,256] = A_f32[M,KD] @ Wt^T + bias -
template<int KD>
__global__ __launch_bounds__(256) void proj_kernel(
    const float* __restrict__ A, const ushort_t* __restrict__ Wt,
    const float* __restrict__ bias, ushort_t* __restrict__ C)
{
    __shared__ ushort_t lA[128 * 40];
    __shared__ ushort_t lB[128 * 40];
    const int tid  = threadIdx.x;
    const int m0   = blockIdx.x * 128;
    const int n0   = blockIdx.y * 128;
    const int lane = tid & 63, wave = tid >> 6;
    const int l15  = lane & 15, quad = lane >> 4;
    const int wrow = (wave >> 1) * 64, wcol = (wave & 1) * 64;
    const int srow = tid >> 1, shalf = tid & 1;

    v4f acc[4][4];
    #pragma unroll
    for (int i = 0; i < 4; ++i)
        #pragma unroll
        for (int j = 0; j < 4; ++j) acc[i][j] = v4f{0.f, 0.f, 0.f, 0.f};

    for (int kt = 0; kt < KD / 32; ++kt) {
        stage_cvt16(A + (size_t)(m0 + srow) * KD + kt * 32 + shalf * 16,
                    &lA[srow * 40 + shalf * 16]);
        stage_copy16(Wt + (size_t)(n0 + srow) * KD + kt * 32 + shalf * 16,
                     &lB[srow * 40 + shalf * 16]);
        __syncthreads();
        v8s af[4], bfr[4];
        #pragma unroll
        for (int rt = 0; rt < 4; ++rt) af[rt]  = *(const v8s*)&lA[(wrow + rt * 16 + l15) * 40 + quad * 8];
        #pragma unroll
        for (int ct = 0; ct < 4; ++ct) bfr[ct] = *(const v8s*)&lB[(wcol + ct * 16 + l15) * 40 + quad * 8];
        #pragma unroll
        for (int rt = 0; rt < 4; ++rt)
            #pragma unroll
            for (int ct = 0; ct < 4; ++ct)
                acc[rt][ct] = mfma16(af[rt], bfr[ct], acc[rt][ct]);
        __syncthreads();
    }

    #pragma unroll
    for (int ct = 0; ct < 4; ++ct) {
        int col = n0 + wcol + ct * 16 + l15;
        float bv = bias[col];
        #pragma unroll
        for (int rt = 0; rt < 4; ++rt)
            #pragma unroll
            for (int r = 0; r < 4; ++r) {
                int row = m0 + wrow + rt * 16 + quad * 4 + r;
                C[(size_t)row * 256 + col] = f2bf(acc[rt][ct][r] + bv);
            }
    }
}

// ---------------- V transpose: Vb[b][m][n] -> Vt[b][n][m] (bf16) ------------
__global__ __launch_bounds__(256) void transpose_v(const ushort_t* __restrict__ Vb, ushort_t* __restrict__ Vt) {
    __shared__ ushort_t t[64 * 72];
    int b = blockIdx.z, m0 = blockIdx.x * 64, n0 = blockIdx.y * 64;
    int tid = threadIdx.x;
    int r = tid >> 2, seg = tid & 3;
    stage_copy16(Vb + (size_t)(b * NN + m0 + r) * HD + n0 + seg * 16, &t[r * 72 + seg * 16]);
    __syncthreads();
    int n = tid >> 2;
    u16x8 p0, p1;
    #pragma unroll
    for (int i = 0; i < 8; ++i) p0[i] = t[(seg * 16 + i) * 72 + n];
    #pragma unroll
    for (int i = 0; i < 8; ++i) p1[i] = t[(seg * 16 + 8 + i) * 72 + n];
    ushort_t* dst = Vt + (size_t)(b * HD + n0 + n) * NN + m0 + seg * 16;
    *(u16x8*)dst = p0;
    *(u16x8*)(dst + 8) = p1;
}

// ---------------- fused attention: QK^T + log(w) -> softmax -> attn + PV-pool
// Block: 512 threads (8 waves), owns M=32 rows of one batch, full N=1024.
// LDS: S[32][SP] fp32 = 131.6 KB -> 1 block/CU.
__global__ __launch_bounds__(512) void attn_kernel(
    const ushort_t* __restrict__ Qb, const ushort_t* __restrict__ Kb,
    const ushort_t* __restrict__ Vt, const float* __restrict__ cw,
    float* __restrict__ attn, float* __restrict__ gpool)
{
    __shared__ float S[32 * SP];
    const int bat = blockIdx.x;          // batch on x -> batch%8 pins to XCD (K/V L2 reuse)
    const int m0  = blockIdx.y * 32;
    const int tid = threadIdx.x;
    const int lane = tid & 63, wave = tid >> 6;
    const int l15 = lane & 15, quad = lane >> 4;

    // ---- Phase 1: S[m][n] = scale*Q@K^T + log(w+1e-8), wave handles 128 cols
    v8s af[2][8];
    #pragma unroll
    for (int rt = 0; rt < 2; ++rt)
        #pragma unroll
        for (int ks = 0; ks < 8; ++ks)
            af[rt][ks] = *(const v8s*)(Qb + (size_t)(bat * NN + m0 + rt * 16 + l15) * HD + ks * 32 + quad * 8);

    const int n0w = wave * 128;
    #pragma unroll 2
    for (int ct = 0; ct < 8; ++ct) {
        const int col = n0w + ct * 16 + l15;
        v8s bfr[8];
        #pragma unroll
        for (int ks = 0; ks < 8; ++ks)
            bfr[ks] = *(const v8s*)(Kb + (size_t)(bat * NN + col) * HD + ks * 32 + quad * 8);
        // prefetch cw for this tile
        float w0[4], w1[4];
        const size_t cwb = ((size_t)bat << 20) + col;
        #pragma unroll
        for (int r = 0; r < 4; ++r) {
            w0[r] = cw[cwb + (size_t)(m0 + quad * 4 + r) * NN];
            w1[r] = cw[cwb + (size_t)(m0 + 16 + quad * 4 + r) * NN];
        }
        v4f acc0 = {0.f, 0.f, 0.f, 0.f}, acc1 = {0.f, 0.f, 0.f, 0.f};
        #pragma unroll
        for (int ks = 0; ks < 8; ++ks) {
            acc0 = mfma16(af[0][ks], bfr[ks], acc0);
            acc1 = mfma16(af[1][ks], bfr[ks], acc1);
        }
        #pragma unroll
        for (int r = 0; r < 4; ++r) {
            const int row0 = quad * 4 + r;
            S[row0 * SP + col]        = acc0[r] * 0.0625f + __logf(w0[r] + 1e-8f);
            S[(16 + row0) * SP + col] = acc1[r] * 0.0625f + __logf(w1[r] + 1e-8f);
        }
    }
    __syncthreads();

    // ---- Phase 2: per-row softmax in LDS, write attn to global
    #pragma unroll 1
    for (int rr = 0; rr < 4; ++rr) {
        const int row = wave * 4 + rr;
        float* Srow = &S[row * SP];
        float4 v[4];
        #pragma unroll
        for (int i = 0; i < 4; ++i) v[i] = *(float4*)(Srow + i * 256 + lane * 4);
        float m = -1e30f;
        #pragma unroll
        for (int i = 0; i < 4; ++i)
            m = fmaxf(m, fmaxf(fmaxf(v[i].x, v[i].y), fmaxf(v[i].z, v[i].w)));
        #pragma unroll
        for (int off = 1; off <= 32; off <<= 1) m = fmaxf(m, __shfl_xor(m, off));
        float s = 0.f;
        #pragma unroll
        for (int i = 0; i < 4; ++i) {
            v[i].x = __expf(v[i].x - m); v[i].y = __expf(v[i].y - m);
            v[i].z = __expf(v[i].z - m); v[i].w = __expf(v[i].w - m);
            s += v[i].x + v[i].y + v[i].z + v[i].w;
        }
        #pragma unroll
        for (int off = 1; off <= 32; off <<= 1) s += __shfl_xor(s, off);
        const float inv = 1.0f / s;
        float* grow = attn + ((size_t)bat << 20) + (size_t)(m0 + row) * NN;
        #pragma unroll
        for (int i = 0; i < 4; ++i) {
            v[i].x *= inv; v[i].y *= inv; v[i].z *= inv; v[i].w *= inv;
            *(float4*)(Srow + i * 256 + lane * 4) = v[i];
            *(float4*)(grow + i * 256 + lane * 4) = v[i];
        }
    }
    __syncthreads();

    // ---- Phase 3: O-colsum of P @ V  (P fp32 in LDS, V from Vt global)
    v4f o[2][2];
    #pragma unroll
    for (int rt = 0; rt < 2; ++rt)
        #pragma unroll
        for (int ct = 0; ct < 2; ++ct) o[rt][ct] = v4f{0.f, 0.f, 0.f, 0.f};
    const int pn0 = wave * 32;
    #pragma unroll 2
    for (int kt = 0; kt < 32; ++kt) {
        v8s a2[2];
        #pragma unroll
        for (int rt = 0; rt < 2; ++rt) {
            const float* p = &S[(rt * 16 + l15) * SP + kt * 32 + quad * 8];
            float4 x = *(const float4*)p;
            float4 y = *(const float4*)(p + 4);
            u16x8 pk;
            pk[0]=f2bf_fast(x.x); pk[1]=f2bf_fast(x.y); pk[2]=f2bf_fast(x.z); pk[3]=f2bf_fast(x.w);
            pk[4]=f2bf_fast(y.x); pk[5]=f2bf_fast(y.y); pk[6]=f2bf_fast(y.z); pk[7]=f2bf_fast(y.w);
            a2[rt] = (v8s)pk;
        }
        #pragma unroll
        for (int ct = 0; ct < 2; ++ct) {
            v8s b2 = *(const v8s*)(Vt + (size_t)(bat * HD + pn0 + ct * 16 + l15) * NN + kt * 32 + quad * 8);
            o[0][ct] = mfma16(a2[0], b2, o[0][ct]);
            o[1][ct] = mfma16(a2[1], b2, o[1][ct]);
        }
    }
    #pragma unroll
    for (int ct = 0; ct < 2; ++ct) {
        float s = 0.f;
        #pragma unroll
        for (int rt = 0; rt < 2; ++rt)
            #pragma unroll
            for (int r = 0; r < 4; ++r) s += o[rt][ct][r];
        s += __shfl_xor(s, 16);
        s += __shfl_xor(s, 32);
        if (quad == 0) atomicAdd(&gpool[bat * HD + pn0 + ct * 16 + l15], s);
    }
}

// ---------------- tails (fp32 vector) ---------------------------------------
__global__ void tail1_kernel(const float* __restrict__ pooled, const float* __restrict__ gpool,
                             const float* __restrict__ Wcp, const float* __restrict__ bcp,
                             const float* __restrict__ Wgp, const float* __restrict__ bgp,
                             float* __restrict__ combined)
{
    int idx = blockIdx.x * 256 + threadIdx.x;  // 32*1280
    int b = idx / OD, c = idx % OD;
    float acc;
    if (c < 640) {
        acc = bcp[c];
        const float* a = pooled + b * CD;
        for (int k = 0; k < CD; ++k) acc += a[k] * Wcp[k * 640 + c];
    } else {
        int c2 = c - 640;
        acc = bgp[c2];
        const float* g = gpool + b * HD;
        for (int k = 0; k < HD; ++k) acc += (g[k] * (1.f / 1024.f)) * Wgp[k * 640 + c2];
    }
    combined[idx] = acc;
}

__global__ void tail2_kernel(const float* __restrict__ combined, const float* __restrict__ Wf1,
                             const float* __restrict__ bf1,
                             const float* __restrict__ g, const float* __restrict__ be,
                             const float* __restrict__ mn, const float* __restrict__ vr,
                             float* __restrict__ h)
{
    int idx = blockIdx.x * 256 + threadIdx.x;
    int b = idx / OD, c = idx % OD;
    float acc = bf1[c];
    const float* a = combined + b * OD;
    for (int k = 0; k < OD; ++k) acc += a[k] * Wf1[k * OD + c];
    float x = (acc - mn[c]) * rsqrtf(vr[c] + 1e-5f) * g[c] + be[c];
    h[idx] = fmaxf(x, 0.f);
}

__global__ void tail3_kernel(const float* __restrict__ h, const float* __restrict__ Wf2,
                             const float* __restrict__ bf2, float* __restrict__ out)
{
    int idx = blockIdx.x * 256 + threadIdx.x;
    int b = idx / OD, c = idx % OD;
    float acc = bf2[c];
    const float* a = h + b * OD;
    for (int k = 0; k < OD; ++k) acc += a[k] * Wf2[k * OD + c];
    out[idx] = acc;
}

// ---------------- launch ----------------------------------------------------
extern "C" void kernel_launch(void* const* d_in, const int* in_sizes, int n_in,
                              void* d_out, int out_size, void* d_ws, size_t ws_size,
                              hipStream_t stream)
{
    const float* cf  = (const float*)d_in[0];
    const float* gf  = (const float*)d_in[1];
    const float* cw  = (const float*)d_in[2];
    const float* Wq  = (const float*)d_in[3];  const float* bq  = (const float*)d_in[4];
    const float* Wk  = (const float*)d_in[5];  const float* bk  = (const float*)d_in[6];
    const float* Wv  = (const float*)d_in[7];  const float* bv  = (const float*)d_in[8];
    const float* Wcp = (const float*)d_in[9];  const float* bcp = (const float*)d_in[10];
    const float* Wgp = (const float*)d_in[11]; const float* bgp = (const float*)d_in[12];
    const float* Wf1 = (const float*)d_in[13]; const float* bf1 = (const float*)d_in[14];
    const float* bng = (const float*)d_in[15]; const float* bnb = (const float*)d_in[16];
    const float* bnm = (const float*)d_in[17]; const float* bnv = (const float*)d_in[18];
    const float* Wf2 = (const float*)d_in[19]; const float* bf2 = (const float*)d_in[20];

    float* out  = (float*)d_out;         // [32,1280]
    float* attn = out + NB * OD;         // [32,1024,1024] fp32

    char* w = (char*)d_ws;
    ushort_t* Qb  = (ushort_t*)w; w += (size_t)NB * NN * HD * 2;
    ushort_t* Kb  = (ushort_t*)w; w += (size_t)NB * NN * HD * 2;
    ushort_t* Vb  = (ushort_t*)w; w += (size_t)NB * NN * HD * 2;
    ushort_t* Vt  = (ushort_t*)w; w += (size_t)NB * NN * HD * 2;
    ushort_t* Wqt = (ushort_t*)w; w += (size_t)HD * CD * 2;
    ushort_t* Wkt = (ushort_t*)w; w += (size_t)HD * GD * 2;
    ushort_t* Wvt = (ushort_t*)w; w += (size_t)HD * GD * 2;
    float* pooled   = (float*)w; w += (size_t)NB * CD * 4;   // keep pooled+gpool adjacent
    float* gpool    = (float*)w; w += (size_t)NB * HD * 4;
    float* combined = (float*)w; w += (size_t)NB * OD * 4;
    float* hbuf     = (float*)w; w += (size_t)NB * OD * 4;

    // zero pooled (28672) + gpool (8192) in one pass (contiguous)
    zero_kernel<<<dim3((NB * CD + NB * HD + 255) / 256), dim3(256), 0, stream>>>(pooled, NB * CD + NB * HD);
    convw_kernel<<<dim3(CD), dim3(256), 0, stream>>>(Wq, Wqt, CD);
    convw_kernel<<<dim3(GD), dim3(256), 0, stream>>>(Wk, Wkt, GD);
    convw_kernel<<<dim3(GD), dim3(256), 0, stream>>>(Wv, Wvt, GD);
    pool_kernel<<<dim3(8, 32), dim3(256), 0, stream>>>(cf, pooled);

    proj_kernel<CD><<<dim3(256, 2), dim3(256), 0, stream>>>(cf, Wqt, bq, Qb);
    proj_kernel<GD><<<dim3(256, 2), dim3(256), 0, stream>>>(gf, Wkt, bk, Kb);
    proj_kernel<GD><<<dim3(256, 2), dim3(256), 0, stream>>>(gf, Wvt, bv, Vb);
    transpose_v<<<dim3(16, 4, 32), dim3(256), 0, stream>>>(Vb, Vt);

    attn_kernel<<<dim3(32, 32), dim3(512), 0, stream>>>(Qb, Kb, Vt, cw, attn, gpool);

    tail1_kernel<<<dim3(160), dim3(256), 0, stream>>>(pooled, gpool, Wcp, bcp, Wgp, bgp, combined);
    tail2_kernel<<<dim3(160), dim3(256), 0, stream>>>(combined, Wf1, bf1, bng, bnb, bnm, bnv, hbuf);
    tail3_kernel<<<dim3(160), dim3(256), 0, stream>>>(hbuf, Wf2, bf2, out);
}